// Round 7
// baseline (659.434 us; speedup 1.0000x reference)
//
#include <hip/hip_runtime.h>
#include <hip/hip_bf16.h>
#include <stdint.h>

// ---------------------------------------------------------------------------
// ChebConv with attention + per-(t,k) dropout, MI355X bf16 MFMA implementation
// out[b,t,u,o] = relu( sum_k M[t,k] @ (x[b,t] @ Theta[k]) )
// M[t,k,u,v] = mask(t,k,u,v) ? cheb[k,u,v]*Att[u,v]/0.4 : 0
// mask = threefry2x32 partitionable, key(42), bits = x0^x1   (verified R0)
// B=32 T=12 V=1000(pad 1024) F=O=64 K=3
// ws: M bf16 [36][1024][1024] (75.5MB) | xt bf16 [12][2048][1024] (50.3MB)
//
// R7: R6 (vc-outer, builtin MFMA -> pacc in AGPRs, no spill) + T14
// issue-early/commit-late staging pipeline: next chunk's 8x16B global loads
// issued BEFORE the MFMA burst, ds_write'd after -- hides HBM latency under
// compute. R6 was stage->sync->compute serialized (MfmaUtil 25%, 1 block/CU).
// ---------------------------------------------------------------------------

typedef __attribute__((ext_vector_type(8))) short short8;
typedef __attribute__((ext_vector_type(4))) float f32x4;

__device__ __forceinline__ ushort f2bf(float f) {
  __hip_bfloat16 h = __float2bfloat16(f);
  return *reinterpret_cast<ushort*>(&h);
}

__device__ __forceinline__ void threefry2x32(uint32_t c0, uint32_t c1,
                                             uint32_t& o0, uint32_t& o1) {
  const uint32_t ks0 = 0u;
  const uint32_t ks1 = 42u;
  const uint32_t ks2 = ks0 ^ ks1 ^ 0x1BD11BDAu;
  uint32_t x0 = c0 + ks0;
  uint32_t x1 = c1 + ks1;
#define TFR(r) { x0 += x1; x1 = (x1 << (r)) | (x1 >> (32 - (r))); x1 ^= x0; }
  TFR(13) TFR(15) TFR(26) TFR(6)
  x0 += ks1; x1 += ks2 + 1u;
  TFR(17) TFR(29) TFR(16) TFR(24)
  x0 += ks2; x1 += ks0 + 2u;
  TFR(13) TFR(15) TFR(26) TFR(6)
  x0 += ks0; x1 += ks1 + 3u;
  TFR(17) TFR(29) TFR(16) TFR(24)
  x0 += ks1; x1 += ks2 + 4u;
  TFR(13) TFR(15) TFR(26) TFR(6)
  x0 += ks2; x1 += ks0 + 5u;
#undef TFR
  o0 = x0; o1 = x1;
}

// ---------------------------------------------------------------------------
// Kernel 1: build masked M (bf16) into ws, padded [36][1024][1024].
// ---------------------------------------------------------------------------
__global__ void build_m(const float* __restrict__ Att,
                        const float* __restrict__ cheb,
                        ushort* __restrict__ Mws) {
  const uint32_t idx = blockIdx.x * 256u + threadIdx.x;
  const uint32_t vp = idx & 1023u;
  const uint32_t up = (idx >> 10) & 1023u;
  const uint32_t tk = idx >> 20;
  float val = 0.f;
  if ((vp < 1000u) & (up < 1000u)) {
    const uint32_t flat = (tk * 1000u + up) * 1000u + vp;
    uint32_t o0, o1;
    threefry2x32(0u, flat, o0, o1);
    const uint32_t bits = o0 ^ o1;
    const float u = __uint_as_float((bits >> 9) | 0x3f800000u) - 1.0f;
    if (u < 0.4f) {
      val = cheb[(tk % 3u) * 1000000u + up * 1000u + vp] *
            Att[up * 1000u + vp] * 2.5f;
    }
  }
  Mws[idx] = f2bf(val);
}

// ---------------------------------------------------------------------------
// Kernel 2: xt[t][n=b*64+f][v(1024 pad)] bf16  <-  x[b][t][v][f] f32
// ---------------------------------------------------------------------------
__global__ void transpose_x(const float* __restrict__ x,
                            ushort* __restrict__ xt) {
  __shared__ float lt[64][65];
  const int vc = blockIdx.x, t = blockIdx.y, b = blockIdx.z;
  const int tid = threadIdx.x;
  const int v0 = vc * 64;
#pragma unroll
  for (int i = 0; i < 4; ++i) {
    const int c = i * 256 + tid;
    const int vi = c >> 4, f4 = c & 15;
    float4 q = make_float4(0.f, 0.f, 0.f, 0.f);
    if (v0 + vi < 1000)
      q = *(const float4*)(x + ((((size_t)b * 12 + t) * 1000 + v0 + vi) << 6) + f4 * 4);
    lt[f4 * 4 + 0][vi] = q.x;
    lt[f4 * 4 + 1][vi] = q.y;
    lt[f4 * 4 + 2][vi] = q.z;
    lt[f4 * 4 + 3][vi] = q.w;
  }
  __syncthreads();
  const int f = tid >> 2, g = tid & 3;
  alignas(16) ushort tmp[16];
#pragma unroll
  for (int j = 0; j < 16; ++j) tmp[j] = f2bf(lt[f][g * 16 + j]);
  const size_t base = ((size_t)(t * 2048 + b * 64 + f)) << 10;
  *(uint4*)(xt + base + v0 + g * 16)     = *(const uint4*)&tmp[0];
  *(uint4*)(xt + base + v0 + g * 16 + 8) = *(const uint4*)&tmp[8];
}

// ---------------------------------------------------------------------------
// Kernel 3: main fused GEMM.  Block = 512 thr (8 waves), tile 128(u) x 128(n)
// per t.  Wave tile 32u x 64n.  vc-outer loop with issue-early/commit-late
// staging: per 64-wide chunk stage A0|A1|A2|B (64KB), B frags read once,
// 48 MFMA into pacc[3] (AGPR-resident via builtin).
// Stage 2 (k unrolled): pacc[k] -> sP(bf16) -> oacc += P @ ThetaT[k].
// LDS 64KB: sA 3x[128][64] @0 | sB [128][64] @24576; sP (8 waves x 32x72)
// overlays sA; sTh [64][72] overlays sB.
// Content XOR-swizzle (verified R3): LDS[r][c16B] = G[r][c ^ (r&7)].
// ---------------------------------------------------------------------------
#define LDT 72

#define MFMA(a, b, c) __builtin_amdgcn_mfma_f32_16x16x32_bf16((a), (b), (c), 0, 0, 0)

__global__ __launch_bounds__(512, 1)
void cheb_main(const ushort* __restrict__ Mws, const ushort* __restrict__ xt,
               const float* __restrict__ Theta, float* __restrict__ out) {
  __shared__ __align__(16) ushort smem[32768];  // 64 KB
  const int tid = threadIdx.x;
  const int lane = tid & 63;
  const int w = tid >> 6;              // wave 0..7
  const int wu = w >> 1, wn = w & 1;   // wave tile: u = wu*32, n = wn*64
  const int quad = lane >> 4, l15 = lane & 15;
  const int nt = blockIdx.x, ut = blockIdx.y, t = blockIdx.z;
  const int u0 = ut * 128, n0 = nt * 128;

  ushort* sA  = smem;            // 3 * 8192
  ushort* sB  = smem + 24576;    // 8192
  ushort* sP  = smem + w * (32 * LDT);  // stage-2 overlay of sA
  ushort* sTh = smem + 24576;           // stage-2 overlay of sB

  const int srow = lane >> 3;            // 0..7
  const int gchunk = (lane & 7) ^ srow;  // pre-swizzled source chunk
  const int rsw = l15 & 7;               // read-side swizzle key (= row&7)

  const size_t mbase = (size_t)(t * 3) << 20;
  const size_t xrow0 = (size_t)(t * 2048 + n0);

  // ---- staging helpers: 8 x 16B per thread per chunk (A0,A1,A2,B) ----
  uint4 pf[8];
  auto issue = [&](int vc) {
#pragma unroll
    for (int q = 0; q < 8; ++q) {
      const int r = q >> 1, j = q & 1;
      const int rr = 8 * (w * 2 + j) + srow;
      const ushort* src = (r < 3)
          ? Mws + mbase + ((size_t)r << 20) + ((size_t)(u0 + rr) << 10) + vc * 64 + gchunk * 8
          : xt + ((xrow0 + rr) << 10) + vc * 64 + gchunk * 8;
      pf[q] = *(const uint4*)src;
    }
  };
  auto commit = [&]() {
#pragma unroll
    for (int q = 0; q < 8; ++q) {
      const int r = q >> 1, j = q & 1;
      ushort* dst = (r < 3) ? sA + r * 8192 + (w * 2 + j) * 512 + lane * 8
                            : sB + (w * 2 + j) * 512 + lane * 8;
      *(uint4*)dst = pf[q];
    }
  };

  f32x4 pacc[3][2][4];
#pragma unroll
  for (int k = 0; k < 3; ++k)
#pragma unroll
    for (int i = 0; i < 2; ++i)
#pragma unroll
      for (int j = 0; j < 4; ++j) pacc[k][i][j] = f32x4{0.f, 0.f, 0.f, 0.f};

  // ---- prologue: stage chunk 0 ----
  issue(0);
  commit();
  __syncthreads();

  // ---- main K loop: 16 chunks of 64, issue-early / commit-late ----
#pragma unroll 1
  for (int vc = 0; vc < 16; ++vc) {
    if (vc < 15) issue(vc + 1);   // loads in flight during MFMA burst
    __builtin_amdgcn_s_setprio(1);
#pragma unroll
    for (int ks = 0; ks < 2; ++ks) {
      short8 bv[4];
#pragma unroll
      for (int ni = 0; ni < 4; ++ni) {
        const int row = wn * 64 + ni * 16 + l15;
        bv[ni] = *(const short8*)&sB[row * 64 + (((ks * 4 + quad) ^ rsw) * 8)];
      }
#pragma unroll
      for (int k = 0; k < 3; ++k) {
        short8 av[2];
#pragma unroll
        for (int mi = 0; mi < 2; ++mi) {
          const int row = wu * 32 + mi * 16 + l15;
          av[mi] = *(const short8*)&sA[k * 8192 + row * 64 + (((ks * 4 + quad) ^ rsw) * 8)];
        }
#pragma unroll
        for (int mi = 0; mi < 2; ++mi)
#pragma unroll
          for (int ni = 0; ni < 4; ++ni)
            pacc[k][mi][ni] = MFMA(av[mi], bv[ni], pacc[k][mi][ni]);
      }
    }
    __builtin_amdgcn_s_setprio(0);
    __syncthreads();               // all waves done reading this chunk
    if (vc < 15) {
      commit();                    // ds_write next chunk (dep-waits pf data)
      __syncthreads();             // next chunk visible to all
    }
  }

  // ---- stage 2: oacc += P_k @ ThetaT[k], k fully unrolled ----
  f32x4 oacc[2][4];
#pragma unroll
  for (int i = 0; i < 2; ++i)
#pragma unroll
    for (int j = 0; j < 4; ++j) oacc[i][j] = f32x4{0.f, 0.f, 0.f, 0.f};

#pragma unroll
  for (int k = 0; k < 3; ++k) {
    __syncthreads();  // prev readers of sP/sTh done
#pragma unroll
    for (int mi = 0; mi < 2; ++mi)
#pragma unroll
      for (int ni = 0; ni < 4; ++ni)
#pragma unroll
        for (int r = 0; r < 4; ++r)
          sP[(mi * 16 + quad * 4 + r) * LDT + ni * 16 + l15] = f2bf(pacc[k][mi][ni][r]);
    for (int e = tid; e < 4096; e += 512) {
      const int f = e >> 6, o = e & 63;
      sTh[o * LDT + f] = f2bf(Theta[k * 4096 + e]);
    }
    __syncthreads();
#pragma unroll
    for (int ks = 0; ks < 2; ++ks) {
      short8 a2[2], b2[4];
#pragma unroll
      for (int mi = 0; mi < 2; ++mi)
        a2[mi] = *(const short8*)&sP[(mi * 16 + l15) * LDT + ks * 32 + quad * 8];
#pragma unroll
      for (int ni = 0; ni < 4; ++ni)
        b2[ni] = *(const short8*)&sTh[(ni * 16 + l15) * LDT + ks * 32 + quad * 8];
#pragma unroll
      for (int mi = 0; mi < 2; ++mi)
#pragma unroll
        for (int ni = 0; ni < 4; ++ni)
          oacc[mi][ni] = MFMA(a2[mi], b2[ni], oacc[mi][ni]);
    }
  }

  // ---- epilogue: relu + store ----
#pragma unroll
  for (int mi = 0; mi < 2; ++mi) {
    const int u_base = u0 + wu * 32 + mi * 16 + quad * 4;
#pragma unroll
    for (int ni = 0; ni < 4; ++ni) {
      const int n = n0 + wn * 64 + ni * 16 + l15;
      const int b = n >> 6, oo = n & 63;
      float* op = out + (((size_t)b * 12 + t) * 1000) * 64 + oo;
#pragma unroll
      for (int r = 0; r < 4; ++r) {
        const int u = u_base + r;
        if (u < 1000) op[(size_t)u * 64] = fmaxf(oacc[mi][ni][r], 0.f);
      }
    }
  }
}

// ---------------------------------------------------------------------------
extern "C" void kernel_launch(void* const* d_in, const int* in_sizes, int n_in,
                              void* d_out, int out_size, void* d_ws, size_t ws_size,
                              hipStream_t stream) {
  const float* x     = (const float*)d_in[0];
  const float* Att   = (const float*)d_in[1];
  const float* cheb  = (const float*)d_in[2];
  const float* Theta = (const float*)d_in[3];
  float* out = (float*)d_out;

  ushort* Mws = (ushort*)d_ws;                 // 36*1024*1024 bf16
  ushort* xtw = Mws + 37748736ull;             // 12*2048*1024 bf16
  // requires ws_size >= 125,829,120 bytes

  build_m<<<147456, 256, 0, stream>>>(Att, cheb, Mws);
  transpose_x<<<dim3(16, 12, 32), 256, 0, stream>>>(x, xtw);
  cheb_main<<<dim3(16, 8, 12), 512, 0, stream>>>(Mws, xtw, Theta, out);
}

// Round 8
// 301.643 us; speedup vs baseline: 2.1861x; 2.1861x over previous
//
#include <hip/hip_runtime.h>
#include <hip/hip_bf16.h>
#include <stdint.h>

// ---------------------------------------------------------------------------
// ChebConv with attention + per-(t,k) dropout, MI355X bf16 MFMA implementation
// out[b,t,u,o] = relu( sum_k M[t,k] @ (x[b,t] @ Theta[k]) )
// M[t,k,u,v] = mask(t,k,u,v) ? cheb[k,u,v]*Att[u,v]/0.4 : 0
// mask = threefry2x32 partitionable, key(42), bits = x0^x1   (verified R0)
// B=32 T=12 V=1000(pad 1024) F=O=64 K=3
// ws: M bf16 [36][1024][1024] (75.5MB) | xt bf16 [12][2048][1024] (50.3MB)
//
// R8: R7's issue-early/commit-late pipeline with the LAMBDAS REMOVED.
// R4/R5/R7 all spilled ~1.4-2GB scratch (VGPR=80) because pf[8] was
// captured by reference into issue()/commit() closures -> not SROA'd ->
// scratch round-trip per chunk. R6 (inline, no pf) had no spill. Fix:
// named uint4 locals p0..p7 + explicit unrolled load/ds_write code.
// ---------------------------------------------------------------------------

typedef __attribute__((ext_vector_type(8))) short short8;
typedef __attribute__((ext_vector_type(4))) float f32x4;

__device__ __forceinline__ ushort f2bf(float f) {
  __hip_bfloat16 h = __float2bfloat16(f);
  return *reinterpret_cast<ushort*>(&h);
}

__device__ __forceinline__ void threefry2x32(uint32_t c0, uint32_t c1,
                                             uint32_t& o0, uint32_t& o1) {
  const uint32_t ks0 = 0u;
  const uint32_t ks1 = 42u;
  const uint32_t ks2 = ks0 ^ ks1 ^ 0x1BD11BDAu;
  uint32_t x0 = c0 + ks0;
  uint32_t x1 = c1 + ks1;
#define TFR(r) { x0 += x1; x1 = (x1 << (r)) | (x1 >> (32 - (r))); x1 ^= x0; }
  TFR(13) TFR(15) TFR(26) TFR(6)
  x0 += ks1; x1 += ks2 + 1u;
  TFR(17) TFR(29) TFR(16) TFR(24)
  x0 += ks2; x1 += ks0 + 2u;
  TFR(13) TFR(15) TFR(26) TFR(6)
  x0 += ks0; x1 += ks1 + 3u;
  TFR(17) TFR(29) TFR(16) TFR(24)
  x0 += ks1; x1 += ks2 + 4u;
  TFR(13) TFR(15) TFR(26) TFR(6)
  x0 += ks2; x1 += ks0 + 5u;
#undef TFR
  o0 = x0; o1 = x1;
}

// ---------------------------------------------------------------------------
// Kernel 1: build masked M (bf16) into ws, padded [36][1024][1024].
// ---------------------------------------------------------------------------
__global__ void build_m(const float* __restrict__ Att,
                        const float* __restrict__ cheb,
                        ushort* __restrict__ Mws) {
  const uint32_t idx = blockIdx.x * 256u + threadIdx.x;
  const uint32_t vp = idx & 1023u;
  const uint32_t up = (idx >> 10) & 1023u;
  const uint32_t tk = idx >> 20;
  float val = 0.f;
  if ((vp < 1000u) & (up < 1000u)) {
    const uint32_t flat = (tk * 1000u + up) * 1000u + vp;
    uint32_t o0, o1;
    threefry2x32(0u, flat, o0, o1);
    const uint32_t bits = o0 ^ o1;
    const float u = __uint_as_float((bits >> 9) | 0x3f800000u) - 1.0f;
    if (u < 0.4f) {
      val = cheb[(tk % 3u) * 1000000u + up * 1000u + vp] *
            Att[up * 1000u + vp] * 2.5f;
    }
  }
  Mws[idx] = f2bf(val);
}

// ---------------------------------------------------------------------------
// Kernel 2: xt[t][n=b*64+f][v(1024 pad)] bf16  <-  x[b][t][v][f] f32
// ---------------------------------------------------------------------------
__global__ void transpose_x(const float* __restrict__ x,
                            ushort* __restrict__ xt) {
  __shared__ float lt[64][65];
  const int vc = blockIdx.x, t = blockIdx.y, b = blockIdx.z;
  const int tid = threadIdx.x;
  const int v0 = vc * 64;
#pragma unroll
  for (int i = 0; i < 4; ++i) {
    const int c = i * 256 + tid;
    const int vi = c >> 4, f4 = c & 15;
    float4 q = make_float4(0.f, 0.f, 0.f, 0.f);
    if (v0 + vi < 1000)
      q = *(const float4*)(x + ((((size_t)b * 12 + t) * 1000 + v0 + vi) << 6) + f4 * 4);
    lt[f4 * 4 + 0][vi] = q.x;
    lt[f4 * 4 + 1][vi] = q.y;
    lt[f4 * 4 + 2][vi] = q.z;
    lt[f4 * 4 + 3][vi] = q.w;
  }
  __syncthreads();
  const int f = tid >> 2, g = tid & 3;
  alignas(16) ushort tmp[16];
#pragma unroll
  for (int j = 0; j < 16; ++j) tmp[j] = f2bf(lt[f][g * 16 + j]);
  const size_t base = ((size_t)(t * 2048 + b * 64 + f)) << 10;
  *(uint4*)(xt + base + v0 + g * 16)     = *(const uint4*)&tmp[0];
  *(uint4*)(xt + base + v0 + g * 16 + 8) = *(const uint4*)&tmp[8];
}

// ---------------------------------------------------------------------------
// Kernel 3: main fused GEMM.  Block = 512 thr (8 waves), tile 128(u) x 128(n)
// per t.  Wave tile 32u x 64n.  vc-outer loop, issue-early/commit-late:
// named-local prefetch (p0..p7) of chunk vc+1 issued before the 48-MFMA
// burst on chunk vc; ds_write after the barrier.  pacc[3] AGPR-resident.
// Stage 2 (k unrolled): pacc[k] -> sP(bf16) -> oacc += P @ ThetaT[k].
// LDS 64KB: sA 3x[128][64] @0 | sB [128][64] @24576; sP (8 waves x 32x72)
// overlays sA; sTh [64][72] overlays sB.
// Content XOR-swizzle (verified R3): LDS[r][c16B] = G[r][c ^ (r&7)].
// ---------------------------------------------------------------------------
#define LDT 72

#define MFMA(a, b, c) __builtin_amdgcn_mfma_f32_16x16x32_bf16((a), (b), (c), 0, 0, 0)

__global__ __launch_bounds__(512, 1)
void cheb_main(const ushort* __restrict__ Mws, const ushort* __restrict__ xt,
               const float* __restrict__ Theta, float* __restrict__ out) {
  __shared__ __align__(16) ushort smem[32768];  // 64 KB
  const int tid = threadIdx.x;
  const int lane = tid & 63;
  const int w = tid >> 6;              // wave 0..7
  const int wu = w >> 1, wn = w & 1;   // wave tile: u = wu*32, n = wn*64
  const int quad = lane >> 4, l15 = lane & 15;
  const int nt = blockIdx.x, ut = blockIdx.y, t = blockIdx.z;
  const int u0 = ut * 128, n0 = nt * 128;

  ushort* sA  = smem;            // 3 * 8192
  ushort* sB  = smem + 24576;    // 8192
  ushort* sP  = smem + w * (32 * LDT);  // stage-2 overlay of sA
  ushort* sTh = smem + 24576;           // stage-2 overlay of sB

  const int srow = lane >> 3;            // 0..7
  const int gchunk = (lane & 7) ^ srow;  // pre-swizzled source chunk
  const int rsw = l15 & 7;               // read-side swizzle key (= row&7)

  const size_t mbase = (size_t)(t * 3) << 20;
  const size_t xrow0 = (size_t)(t * 2048 + n0);

  // per-thread staging geometry (all wave-uniform except srow/gchunk/lane)
  const int rr0 = 8 * (w * 2 + 0) + srow;     // tile rows this thread stages
  const int rr1 = 8 * (w * 2 + 1) + srow;
  const size_t ga0 = mbase + ((size_t)(u0 + rr0) << 10) + gchunk * 8;
  const size_t ga1 = mbase + ((size_t)(u0 + rr1) << 10) + gchunk * 8;
  const size_t gx0 = ((xrow0 + rr0) << 10) + gchunk * 8;
  const size_t gx1 = ((xrow0 + rr1) << 10) + gchunk * 8;
  const int da0 = (w * 2 + 0) * 512 + lane * 8;   // lane-linear LDS dests
  const int da1 = (w * 2 + 1) * 512 + lane * 8;

  f32x4 pacc[3][2][4];
#pragma unroll
  for (int k = 0; k < 3; ++k)
#pragma unroll
    for (int i = 0; i < 2; ++i)
#pragma unroll
      for (int j = 0; j < 4; ++j) pacc[k][i][j] = f32x4{0.f, 0.f, 0.f, 0.f};

  // ---- prologue: stage chunk 0 (inline, no lambda) ----
  {
    const uint4 q0 = *(const uint4*)(Mws + ga0);
    const uint4 q1 = *(const uint4*)(Mws + ga1);
    const uint4 q2 = *(const uint4*)(Mws + ga0 + (1u << 20));
    const uint4 q3 = *(const uint4*)(Mws + ga1 + (1u << 20));
    const uint4 q4 = *(const uint4*)(Mws + ga0 + (2u << 20));
    const uint4 q5 = *(const uint4*)(Mws + ga1 + (2u << 20));
    const uint4 q6 = *(const uint4*)(xt + gx0);
    const uint4 q7 = *(const uint4*)(xt + gx1);
    *(uint4*)&sA[da0]          = q0;
    *(uint4*)&sA[da1]          = q1;
    *(uint4*)&sA[8192 + da0]   = q2;
    *(uint4*)&sA[8192 + da1]   = q3;
    *(uint4*)&sA[16384 + da0]  = q4;
    *(uint4*)&sA[16384 + da1]  = q5;
    *(uint4*)&sB[da0]          = q6;
    *(uint4*)&sB[da1]          = q7;
  }
  __syncthreads();

  // ---- main K loop: 16 chunks of 64, issue-early / commit-late ----
#pragma unroll 1
  for (int vc = 0; vc < 16; ++vc) {
    uint4 p0, p1, p2, p3, p4, p5, p6, p7;   // named locals -> registers
    if (vc < 15) {
      const size_t co = (size_t)(vc + 1) * 64;   // element offset of next chunk
      p0 = *(const uint4*)(Mws + ga0 + co);
      p1 = *(const uint4*)(Mws + ga1 + co);
      p2 = *(const uint4*)(Mws + ga0 + (1u << 20) + co);
      p3 = *(const uint4*)(Mws + ga1 + (1u << 20) + co);
      p4 = *(const uint4*)(Mws + ga0 + (2u << 20) + co);
      p5 = *(const uint4*)(Mws + ga1 + (2u << 20) + co);
      p6 = *(const uint4*)(xt + gx0 + co);
      p7 = *(const uint4*)(xt + gx1 + co);
    }
    __builtin_amdgcn_s_setprio(1);
#pragma unroll
    for (int ks = 0; ks < 2; ++ks) {
      short8 bv[4];
#pragma unroll
      for (int ni = 0; ni < 4; ++ni) {
        const int row = wn * 64 + ni * 16 + l15;
        bv[ni] = *(const short8*)&sB[row * 64 + (((ks * 4 + quad) ^ rsw) * 8)];
      }
#pragma unroll
      for (int k = 0; k < 3; ++k) {
        short8 av[2];
#pragma unroll
        for (int mi = 0; mi < 2; ++mi) {
          const int row = wu * 32 + mi * 16 + l15;
          av[mi] = *(const short8*)&sA[k * 8192 + row * 64 + (((ks * 4 + quad) ^ rsw) * 8)];
        }
#pragma unroll
        for (int mi = 0; mi < 2; ++mi)
#pragma unroll
          for (int ni = 0; ni < 4; ++ni)
            pacc[k][mi][ni] = MFMA(av[mi], bv[ni], pacc[k][mi][ni]);
      }
    }
    __builtin_amdgcn_s_setprio(0);
    __syncthreads();               // all waves done reading this chunk
    if (vc < 15) {
      *(uint4*)&sA[da0]          = p0;
      *(uint4*)&sA[da1]          = p1;
      *(uint4*)&sA[8192 + da0]   = p2;
      *(uint4*)&sA[8192 + da1]   = p3;
      *(uint4*)&sA[16384 + da0]  = p4;
      *(uint4*)&sA[16384 + da1]  = p5;
      *(uint4*)&sB[da0]          = p6;
      *(uint4*)&sB[da1]          = p7;
      __syncthreads();             // next chunk visible to all
    }
  }

  // ---- stage 2: oacc += P_k @ ThetaT[k], k fully unrolled ----
  f32x4 oacc[2][4];
#pragma unroll
  for (int i = 0; i < 2; ++i)
#pragma unroll
    for (int j = 0; j < 4; ++j) oacc[i][j] = f32x4{0.f, 0.f, 0.f, 0.f};

#pragma unroll
  for (int k = 0; k < 3; ++k) {
    __syncthreads();  // prev readers of sP/sTh done
#pragma unroll
    for (int mi = 0; mi < 2; ++mi)
#pragma unroll
      for (int ni = 0; ni < 4; ++ni)
#pragma unroll
        for (int r = 0; r < 4; ++r)
          sP[(mi * 16 + quad * 4 + r) * LDT + ni * 16 + l15] = f2bf(pacc[k][mi][ni][r]);
    for (int e = tid; e < 4096; e += 512) {
      const int f = e >> 6, o = e & 63;
      sTh[o * LDT + f] = f2bf(Theta[k * 4096 + e]);
    }
    __syncthreads();
#pragma unroll
    for (int ks = 0; ks < 2; ++ks) {
      short8 a2[2], b2[4];
#pragma unroll
      for (int mi = 0; mi < 2; ++mi)
        a2[mi] = *(const short8*)&sP[(mi * 16 + l15) * LDT + ks * 32 + quad * 8];
#pragma unroll
      for (int ni = 0; ni < 4; ++ni)
        b2[ni] = *(const short8*)&sTh[(ni * 16 + l15) * LDT + ks * 32 + quad * 8];
#pragma unroll
      for (int mi = 0; mi < 2; ++mi)
#pragma unroll
        for (int ni = 0; ni < 4; ++ni)
          oacc[mi][ni] = MFMA(a2[mi], b2[ni], oacc[mi][ni]);
    }
  }

  // ---- epilogue: relu + store ----
#pragma unroll
  for (int mi = 0; mi < 2; ++mi) {
    const int u_base = u0 + wu * 32 + mi * 16 + quad * 4;
#pragma unroll
    for (int ni = 0; ni < 4; ++ni) {
      const int n = n0 + wn * 64 + ni * 16 + l15;
      const int b = n >> 6, oo = n & 63;
      float* op = out + (((size_t)b * 12 + t) * 1000) * 64 + oo;
#pragma unroll
      for (int r = 0; r < 4; ++r) {
        const int u = u_base + r;
        if (u < 1000) op[(size_t)u * 64] = fmaxf(oacc[mi][ni][r], 0.f);
      }
    }
  }
}

// ---------------------------------------------------------------------------
extern "C" void kernel_launch(void* const* d_in, const int* in_sizes, int n_in,
                              void* d_out, int out_size, void* d_ws, size_t ws_size,
                              hipStream_t stream) {
  const float* x     = (const float*)d_in[0];
  const float* Att   = (const float*)d_in[1];
  const float* cheb  = (const float*)d_in[2];
  const float* Theta = (const float*)d_in[3];
  float* out = (float*)d_out;

  ushort* Mws = (ushort*)d_ws;                 // 36*1024*1024 bf16
  ushort* xtw = Mws + 37748736ull;             // 12*2048*1024 bf16
  // requires ws_size >= 125,829,120 bytes

  build_m<<<147456, 256, 0, stream>>>(Att, cheb, Mws);
  transpose_x<<<dim3(16, 12, 32), 256, 0, stream>>>(x, xtw);
  cheb_main<<<dim3(16, 8, 12), 512, 0, stream>>>(Mws, xtw, Theta, out);
}

// Round 9
// 286.897 us; speedup vs baseline: 2.2985x; 1.0514x over previous
//
#include <hip/hip_runtime.h>
#include <hip/hip_bf16.h>
#include <stdint.h>

// ---------------------------------------------------------------------------
// ChebConv with attention + per-(t,k) dropout, MI355X bf16 MFMA implementation
// out[b,t,u,o] = relu( sum_k M[t,k] @ (x[b,t] @ Theta[k]) )
// M[t,k,u,v] = mask(t,k,u,v) ? cheb[k,u,v]*Att[u,v]/0.4 : 0
// mask = threefry2x32 partitionable, key(42), bits = x0^x1   (verified R0)
// B=32 T=12 V=1000(pad 1024) F=O=64 K=3
// ws: M bf16 [36][1024][1024] (75.5MB) | xt bf16 [12][2048][1024] (50.3MB)
//
// R9: depth-2 double-buffered LDS (2 x 64KB). Per chunk: MFMA on buf[cur],
// commit prefetch -> buf[cur^1], issue chunk+2, ONE barrier. Ping-pong
// register sets p/q (loop unrolled x2) avoid commit/issue WAR serialization.
// R8 (depth-1, 2 barriers/chunk) was stall-bound: MfmaUtil 30% vs the ~88%
// LDS-BW structural ceiling. All staging = named locals + macros (the
// lambda/array/dyn-index scratch-spill traps from R4/R5/R7 stay banned).
// ---------------------------------------------------------------------------

typedef __attribute__((ext_vector_type(8))) short short8;
typedef __attribute__((ext_vector_type(4))) float f32x4;

__device__ __forceinline__ ushort f2bf(float f) {
  __hip_bfloat16 h = __float2bfloat16(f);
  return *reinterpret_cast<ushort*>(&h);
}

__device__ __forceinline__ void threefry2x32(uint32_t c0, uint32_t c1,
                                             uint32_t& o0, uint32_t& o1) {
  const uint32_t ks0 = 0u;
  const uint32_t ks1 = 42u;
  const uint32_t ks2 = ks0 ^ ks1 ^ 0x1BD11BDAu;
  uint32_t x0 = c0 + ks0;
  uint32_t x1 = c1 + ks1;
#define TFR(r) { x0 += x1; x1 = (x1 << (r)) | (x1 >> (32 - (r))); x1 ^= x0; }
  TFR(13) TFR(15) TFR(26) TFR(6)
  x0 += ks1; x1 += ks2 + 1u;
  TFR(17) TFR(29) TFR(16) TFR(24)
  x0 += ks2; x1 += ks0 + 2u;
  TFR(13) TFR(15) TFR(26) TFR(6)
  x0 += ks0; x1 += ks1 + 3u;
  TFR(17) TFR(29) TFR(16) TFR(24)
  x0 += ks1; x1 += ks2 + 4u;
  TFR(13) TFR(15) TFR(26) TFR(6)
  x0 += ks2; x1 += ks0 + 5u;
#undef TFR
  o0 = x0; o1 = x1;
}

// ---------------------------------------------------------------------------
// Kernel 1: build masked M (bf16) into ws, padded [36][1024][1024].
// ---------------------------------------------------------------------------
__global__ void build_m(const float* __restrict__ Att,
                        const float* __restrict__ cheb,
                        ushort* __restrict__ Mws) {
  const uint32_t idx = blockIdx.x * 256u + threadIdx.x;
  const uint32_t vp = idx & 1023u;
  const uint32_t up = (idx >> 10) & 1023u;
  const uint32_t tk = idx >> 20;
  float val = 0.f;
  if ((vp < 1000u) & (up < 1000u)) {
    const uint32_t flat = (tk * 1000u + up) * 1000u + vp;
    uint32_t o0, o1;
    threefry2x32(0u, flat, o0, o1);
    const uint32_t bits = o0 ^ o1;
    const float u = __uint_as_float((bits >> 9) | 0x3f800000u) - 1.0f;
    if (u < 0.4f) {
      val = cheb[(tk % 3u) * 1000000u + up * 1000u + vp] *
            Att[up * 1000u + vp] * 2.5f;
    }
  }
  Mws[idx] = f2bf(val);
}

// ---------------------------------------------------------------------------
// Kernel 2: xt[t][n=b*64+f][v(1024 pad)] bf16  <-  x[b][t][v][f] f32
// ---------------------------------------------------------------------------
__global__ void transpose_x(const float* __restrict__ x,
                            ushort* __restrict__ xt) {
  __shared__ float lt[64][65];
  const int vc = blockIdx.x, t = blockIdx.y, b = blockIdx.z;
  const int tid = threadIdx.x;
  const int v0 = vc * 64;
#pragma unroll
  for (int i = 0; i < 4; ++i) {
    const int c = i * 256 + tid;
    const int vi = c >> 4, f4 = c & 15;
    float4 q = make_float4(0.f, 0.f, 0.f, 0.f);
    if (v0 + vi < 1000)
      q = *(const float4*)(x + ((((size_t)b * 12 + t) * 1000 + v0 + vi) << 6) + f4 * 4);
    lt[f4 * 4 + 0][vi] = q.x;
    lt[f4 * 4 + 1][vi] = q.y;
    lt[f4 * 4 + 2][vi] = q.z;
    lt[f4 * 4 + 3][vi] = q.w;
  }
  __syncthreads();
  const int f = tid >> 2, g = tid & 3;
  alignas(16) ushort tmp[16];
#pragma unroll
  for (int j = 0; j < 16; ++j) tmp[j] = f2bf(lt[f][g * 16 + j]);
  const size_t base = ((size_t)(t * 2048 + b * 64 + f)) << 10;
  *(uint4*)(xt + base + v0 + g * 16)     = *(const uint4*)&tmp[0];
  *(uint4*)(xt + base + v0 + g * 16 + 8) = *(const uint4*)&tmp[8];
}

// ---------------------------------------------------------------------------
// Kernel 3: main fused GEMM.  Block = 512 thr (8 waves), tile 128(u) x 128(n)
// per t.  Wave tile 32u x 64n.  vc-outer, DEPTH-2 LDS double buffer:
// buffer = sA 3x[128][64] + sB [128][64] = 64KB; two buffers = 128KB.
// Per chunk: BURST(buf[cur]) -> commit regs -> buf[cur^1] -> issue(+2) ->
// one __syncthreads.  pacc[3] AGPR-resident (builtin MFMA).
// Stage 2 (k unrolled): pacc[k] -> sP(bf16) -> oacc += P @ ThetaT[k].
// sP (8 waves x 32x72) and sTh [64][72] overlay buffer 0 regions.
// Content XOR-swizzle (verified R3): LDS[r][c16B] = G[r][c ^ (r&7)].
// ---------------------------------------------------------------------------
#define LDT 72

#define MFMA(a, b, c) __builtin_amdgcn_mfma_f32_16x16x32_bf16((a), (b), (c), 0, 0, 0)

#define STAGE_LOAD(P0, P1, P2, P3, P4, P5, P6, P7, CO)                        \
  do {                                                                        \
    P0 = *(const uint4*)(Mws + ga0 + (CO));                                   \
    P1 = *(const uint4*)(Mws + ga1 + (CO));                                   \
    P2 = *(const uint4*)(Mws + ga0 + 1048576 + (CO));                         \
    P3 = *(const uint4*)(Mws + ga1 + 1048576 + (CO));                         \
    P4 = *(const uint4*)(Mws + ga0 + 2097152 + (CO));                         \
    P5 = *(const uint4*)(Mws + ga1 + 2097152 + (CO));                         \
    P6 = *(const uint4*)(xt + gx0 + (CO));                                    \
    P7 = *(const uint4*)(xt + gx1 + (CO));                                    \
  } while (0)

#define STAGE_WRITE(P0, P1, P2, P3, P4, P5, P6, P7, BP)                       \
  do {                                                                        \
    *(uint4*)&(BP)[da0]         = P0;                                         \
    *(uint4*)&(BP)[da1]         = P1;                                         \
    *(uint4*)&(BP)[8192 + da0]  = P2;                                         \
    *(uint4*)&(BP)[8192 + da1]  = P3;                                         \
    *(uint4*)&(BP)[16384 + da0] = P4;                                         \
    *(uint4*)&(BP)[16384 + da1] = P5;                                         \
    *(uint4*)&(BP)[24576 + da0] = P6;                                         \
    *(uint4*)&(BP)[24576 + da1] = P7;                                         \
  } while (0)

#define BURST(BP)                                                             \
  do {                                                                        \
    const ushort* sAc = (BP);                                                 \
    const ushort* sBc = (BP) + 24576;                                         \
    _Pragma("unroll")                                                         \
    for (int ks = 0; ks < 2; ++ks) {                                          \
      short8 bv[4];                                                           \
      _Pragma("unroll")                                                       \
      for (int ni = 0; ni < 4; ++ni) {                                        \
        const int row = wn * 64 + ni * 16 + l15;                              \
        bv[ni] = *(const short8*)&sBc[row * 64 + (((ks * 4 + quad) ^ rsw) * 8)]; \
      }                                                                       \
      _Pragma("unroll")                                                       \
      for (int k = 0; k < 3; ++k) {                                           \
        short8 av[2];                                                         \
        _Pragma("unroll")                                                     \
        for (int mi = 0; mi < 2; ++mi) {                                      \
          const int row = wu * 32 + mi * 16 + l15;                            \
          av[mi] = *(const short8*)&sAc[k * 8192 + row * 64 +                 \
                                        (((ks * 4 + quad) ^ rsw) * 8)];       \
        }                                                                     \
        _Pragma("unroll")                                                     \
        for (int mi = 0; mi < 2; ++mi)                                        \
          _Pragma("unroll")                                                   \
          for (int ni = 0; ni < 4; ++ni)                                      \
            pacc[k][mi][ni] = MFMA(av[mi], bv[ni], pacc[k][mi][ni]);          \
      }                                                                       \
    }                                                                         \
  } while (0)

__global__ __launch_bounds__(512, 2)
void cheb_main(const ushort* __restrict__ Mws, const ushort* __restrict__ xt,
               const float* __restrict__ Theta, float* __restrict__ out) {
  __shared__ __align__(16) ushort smem[65536];  // 128 KB: buf0 | buf1
  const int tid = threadIdx.x;
  const int lane = tid & 63;
  const int w = tid >> 6;              // wave 0..7
  const int wu = w >> 1, wn = w & 1;   // wave tile: u = wu*32, n = wn*64
  const int quad = lane >> 4, l15 = lane & 15;
  const int nt = blockIdx.x, ut = blockIdx.y, t = blockIdx.z;
  const int u0 = ut * 128, n0 = nt * 128;

  ushort* buf0 = smem;
  ushort* buf1 = smem + 32768;
  ushort* sP  = smem + w * (32 * LDT);  // stage-2 overlay (buf0)
  ushort* sTh = smem + 24576;           // stage-2 overlay (buf0 sB region)

  const int srow = lane >> 3;            // 0..7
  const int gchunk = (lane & 7) ^ srow;  // pre-swizzled source chunk
  const int rsw = l15 & 7;               // read-side swizzle key (= row&7)

  const size_t mbase = (size_t)(t * 3) << 20;
  const size_t xrow0 = (size_t)(t * 2048 + n0);

  const int rr0 = 8 * (w * 2 + 0) + srow;
  const int rr1 = 8 * (w * 2 + 1) + srow;
  const size_t ga0 = mbase + ((size_t)(u0 + rr0) << 10) + gchunk * 8;
  const size_t ga1 = mbase + ((size_t)(u0 + rr1) << 10) + gchunk * 8;
  const size_t gx0 = ((xrow0 + rr0) << 10) + gchunk * 8;
  const size_t gx1 = ((xrow0 + rr1) << 10) + gchunk * 8;
  const int da0 = (w * 2 + 0) * 512 + lane * 8;
  const int da1 = (w * 2 + 1) * 512 + lane * 8;

  f32x4 pacc[3][2][4];
#pragma unroll
  for (int k = 0; k < 3; ++k)
#pragma unroll
    for (int i = 0; i < 2; ++i)
#pragma unroll
      for (int j = 0; j < 4; ++j) pacc[k][i][j] = f32x4{0.f, 0.f, 0.f, 0.f};

  uint4 p0, p1, p2, p3, p4, p5, p6, p7;
  uint4 q0, q1, q2, q3, q4, q5, q6, q7;

  // ---- prologue: chunk 0 -> buf0 (direct); chunk 1 -> p regs ----
  STAGE_LOAD(q0, q1, q2, q3, q4, q5, q6, q7, 0);
  STAGE_LOAD(p0, p1, p2, p3, p4, p5, p6, p7, 64);
  STAGE_WRITE(q0, q1, q2, q3, q4, q5, q6, q7, buf0);
  __syncthreads();

  // ---- main K loop: 16 chunks, unrolled x2 for p/q ping-pong ----
#pragma unroll 1
  for (int it = 0; it < 8; ++it) {
    const int vc = it * 2;
    // even chunk: read buf0, commit p(chunk vc+1)->buf1, issue vc+2 -> q
    __builtin_amdgcn_s_setprio(1);
    BURST(buf0);
    __builtin_amdgcn_s_setprio(0);
    if (vc < 15) STAGE_WRITE(p0, p1, p2, p3, p4, p5, p6, p7, buf1);
    if (vc < 14) STAGE_LOAD(q0, q1, q2, q3, q4, q5, q6, q7, (size_t)(vc + 2) * 64);
    __syncthreads();
    // odd chunk: read buf1, commit q(chunk vc+2)->buf0, issue vc+3 -> p
    __builtin_amdgcn_s_setprio(1);
    BURST(buf1);
    __builtin_amdgcn_s_setprio(0);
    if (vc + 1 < 15) STAGE_WRITE(q0, q1, q2, q3, q4, q5, q6, q7, buf0);
    if (vc + 1 < 14) STAGE_LOAD(p0, p1, p2, p3, p4, p5, p6, p7, (size_t)(vc + 3) * 64);
    __syncthreads();
  }

  // ---- stage 2: oacc += P_k @ ThetaT[k], k fully unrolled ----
  f32x4 oacc[2][4];
#pragma unroll
  for (int i = 0; i < 2; ++i)
#pragma unroll
    for (int j = 0; j < 4; ++j) oacc[i][j] = f32x4{0.f, 0.f, 0.f, 0.f};

#pragma unroll
  for (int k = 0; k < 3; ++k) {
    __syncthreads();  // prev readers of sP/sTh done
#pragma unroll
    for (int mi = 0; mi < 2; ++mi)
#pragma unroll
      for (int ni = 0; ni < 4; ++ni)
#pragma unroll
        for (int r = 0; r < 4; ++r)
          sP[(mi * 16 + quad * 4 + r) * LDT + ni * 16 + l15] = f2bf(pacc[k][mi][ni][r]);
    for (int e = tid; e < 4096; e += 512) {
      const int f = e >> 6, o = e & 63;
      sTh[o * LDT + f] = f2bf(Theta[k * 4096 + e]);
    }
    __syncthreads();
#pragma unroll
    for (int ks = 0; ks < 2; ++ks) {
      short8 a2[2], b2[4];
#pragma unroll
      for (int mi = 0; mi < 2; ++mi)
        a2[mi] = *(const short8*)&sP[(mi * 16 + l15) * LDT + ks * 32 + quad * 8];
#pragma unroll
      for (int ni = 0; ni < 4; ++ni)
        b2[ni] = *(const short8*)&sTh[(ni * 16 + l15) * LDT + ks * 32 + quad * 8];
#pragma unroll
      for (int mi = 0; mi < 2; ++mi)
#pragma unroll
        for (int ni = 0; ni < 4; ++ni)
          oacc[mi][ni] = MFMA(a2[mi], b2[ni], oacc[mi][ni]);
    }
  }

  // ---- epilogue: relu + store ----
#pragma unroll
  for (int mi = 0; mi < 2; ++mi) {
    const int u_base = u0 + wu * 32 + mi * 16 + quad * 4;
#pragma unroll
    for (int ni = 0; ni < 4; ++ni) {
      const int n = n0 + wn * 64 + ni * 16 + l15;
      const int b = n >> 6, oo = n & 63;
      float* op = out + (((size_t)b * 12 + t) * 1000) * 64 + oo;
#pragma unroll
      for (int r = 0; r < 4; ++r) {
        const int u = u_base + r;
        if (u < 1000) op[(size_t)u * 64] = fmaxf(oacc[mi][ni][r], 0.f);
      }
    }
  }
}

// ---------------------------------------------------------------------------
extern "C" void kernel_launch(void* const* d_in, const int* in_sizes, int n_in,
                              void* d_out, int out_size, void* d_ws, size_t ws_size,
                              hipStream_t stream) {
  const float* x     = (const float*)d_in[0];
  const float* Att   = (const float*)d_in[1];
  const float* cheb  = (const float*)d_in[2];
  const float* Theta = (const float*)d_in[3];
  float* out = (float*)d_out;

  ushort* Mws = (ushort*)d_ws;                 // 36*1024*1024 bf16
  ushort* xtw = Mws + 37748736ull;             // 12*2048*1024 bf16
  // requires ws_size >= 125,829,120 bytes

  build_m<<<147456, 256, 0, stream>>>(Att, cheb, Mws);
  transpose_x<<<dim3(16, 12, 32), 256, 0, stream>>>(x, xtw);
  cheb_main<<<dim3(16, 8, 12), 512, 0, stream>>>(Mws, xtw, Theta, out);
}